// Round 7
// baseline (676.531 us; speedup 1.0000x reference)
//
#include <hip/hip_runtime.h>
#include <hip/hip_bf16.h>
#include <cstdint>
#include <cstddef>

#define B_ 2
#define N_ 2048
#define F_ 1024
#define H_ 16
#define D_ 64

typedef float f32x4 __attribute__((ext_vector_type(4)));
typedef short s16x8 __attribute__((ext_vector_type(8)));
typedef short s16x4 __attribute__((ext_vector_type(4)));

__device__ __forceinline__ unsigned short f2bf(float f) {
  union { __hip_bfloat16 h; unsigned short u; } c;
  c.h = __float2bfloat16(f);
  return c.u;
}
__device__ __forceinline__ float bf2f(unsigned short u) {
  union { __hip_bfloat16 h; unsigned short u; } c;
  c.u = u;
  return __bfloat162float(c.h);
}

// ---------------------------------------------------------------------
// fp32 -> bf16 bulk convert (8 elems/thread)
// ---------------------------------------------------------------------
__global__ __launch_bounds__(256) void cvt_bf16(const float* __restrict__ in,
                                                unsigned short* __restrict__ out,
                                                int n8) {
  const int t = blockIdx.x * 256 + threadIdx.x;
  if (t >= n8) return;
  const float4* p = (const float4*)in + (size_t)t * 2;
  float4 a = p[0], b = p[1];
  s16x8 o;
  o[0] = f2bf(a.x); o[1] = f2bf(a.y); o[2] = f2bf(a.z); o[3] = f2bf(a.w);
  o[4] = f2bf(b.x); o[5] = f2bf(b.y); o[6] = f2bf(b.z); o[7] = f2bf(b.w);
  *((s16x8*)out + t) = o;
}

// ---------------------------------------------------------------------
// w_qkv fp32 -> bf16 with row permutation: out row colp = c*1024 + h*64 + d
// ---------------------------------------------------------------------
__global__ __launch_bounds__(256) void cvt_wqkv_perm(const float* __restrict__ in,
                                                     unsigned short* __restrict__ out) {
  const int t = blockIdx.x * 256 + threadIdx.x;
  const int rowp = t >> 7;
  const int kk = (t & 127) * 8;
  const int c = rowp >> 10, rem = rowp & 1023;
  const int h = rem >> 6, d = rem & 63;
  const float* p = in + (size_t)(h * 192 + d * 3 + c) * 1024 + kk;
  float4 a = *(const float4*)p, b = *(const float4*)(p + 4);
  s16x8 o;
  o[0] = f2bf(a.x); o[1] = f2bf(a.y); o[2] = f2bf(a.z); o[3] = f2bf(a.w);
  o[4] = f2bf(b.x); o[5] = f2bf(b.y); o[6] = f2bf(b.z); o[7] = f2bf(b.w);
  *((s16x8*)&out[(size_t)rowp * 1024 + kk]) = o;
}

// ---------------------------------------------------------------------
// sum the two j-half fp32 O partials -> bf16 O1
// ---------------------------------------------------------------------
__global__ __launch_bounds__(256) void cvt_sum(const float* __restrict__ a,
                                               const float* __restrict__ b,
                                               unsigned short* __restrict__ out) {
  const int t = blockIdx.x * 256 + threadIdx.x;
  float4 x = *((const float4*)a + t);
  float4 y = *((const float4*)b + t);
  s16x4 o;
  o[0] = f2bf(x.x + y.x); o[1] = f2bf(x.y + y.y);
  o[2] = f2bf(x.z + y.z); o[3] = f2bf(x.w + y.w);
  *((s16x4*)out + t) = o;
}

// ---------------------------------------------------------------------
// MFMA GEMM (unchanged; passed rounds 4-6).
// ---------------------------------------------------------------------
template <int MODE>
__global__ __launch_bounds__(256) void gemm_bf16(const unsigned short* __restrict__ A,
                                                 const unsigned short* __restrict__ W,
                                                 float* __restrict__ o0,
                                                 unsigned short* __restrict__ oQ,
                                                 unsigned short* __restrict__ oK,
                                                 unsigned short* __restrict__ oVt) {
  __shared__ unsigned short As[128 * 72];
  __shared__ unsigned short Bs[128 * 72];
  const int m0 = blockIdx.y * 128, c0 = blockIdx.x * 128;
  const int tid = threadIdx.x;
  const int wave = tid >> 6, lane = tid & 63;
  const int wm = (wave & 1) * 64, wn = (wave >> 1) * 64;
  const int lm = lane & 15, lq = lane >> 4;
  f32x4 acc[4][4] = {};
  for (int k0 = 0; k0 < 1024; k0 += 64) {
#pragma unroll
    for (int it = 0; it < 4; ++it) {
      const int chunk = it * 256 + tid;
      const int row = chunk >> 3, kq = (chunk & 7) * 8;
      *(float4*)&As[row * 72 + kq] = *(const float4*)&A[(size_t)(m0 + row) * 1024 + k0 + kq];
      *(float4*)&Bs[row * 72 + kq] = *(const float4*)&W[(size_t)(c0 + row) * 1024 + k0 + kq];
    }
    __syncthreads();
#pragma unroll
    for (int ks = 0; ks < 2; ++ks) {
      s16x8 af[4], bfr[4];
#pragma unroll
      for (int i = 0; i < 4; ++i) {
        af[i] = *(const s16x8*)&As[(wm + i * 16 + lm) * 72 + ks * 32 + lq * 8];
        bfr[i] = *(const s16x8*)&Bs[(wn + i * 16 + lm) * 72 + ks * 32 + lq * 8];
      }
#pragma unroll
      for (int i = 0; i < 4; ++i)
#pragma unroll
        for (int j = 0; j < 4; ++j)
          acc[i][j] = __builtin_amdgcn_mfma_f32_16x16x32_bf16(af[i], bfr[j], acc[i][j], 0, 0, 0);
    }
    __syncthreads();
  }
  if (MODE == 1) {
#pragma unroll
    for (int i = 0; i < 4; ++i)
#pragma unroll
      for (int j = 0; j < 4; ++j)
#pragma unroll
        for (int r = 0; r < 4; ++r) {
          const int m = m0 + wm + i * 16 + lq * 4 + r;
          const int col = c0 + wn + j * 16 + lm;
          o0[(size_t)m * 1024 + col] = acc[i][j][r];
        }
  } else {
    const int cls = blockIdx.x >> 3;
    const int colbase = (blockIdx.x & 7) * 128;
    if (cls == 0) {
#pragma unroll
      for (int i = 0; i < 4; ++i)
#pragma unroll
        for (int j = 0; j < 4; ++j) {
          const int cl = colbase + wn + j * 16 + lm;
          const int h = cl >> 6, d = cl & 63;
#pragma unroll
          for (int r = 0; r < 4; ++r) {
            const int m = m0 + wm + i * 16 + lq * 4 + r;
            const int bb = m >> 11, n = m & 2047;
            oQ[(((size_t)bb * H_ + h) * N_ + n) * D_ + d] = f2bf(acc[i][j][r]);
          }
        }
    } else if (cls == 1) {
#pragma unroll
      for (int i = 0; i < 4; ++i)
#pragma unroll
        for (int j = 0; j < 4; ++j) {
          const int cl = colbase + wn + j * 16 + lm;
          const int h = cl >> 6, d = cl & 63;
#pragma unroll
          for (int r = 0; r < 4; ++r) {
            const int m = m0 + wm + i * 16 + lq * 4 + r;
            const int bb = m >> 11, n = m & 2047;
            const size_t idx = (((size_t)bb * H_ + h) * N_ + n) * D_ + d;
            o0[idx] = acc[i][j][r];
            oK[idx] = f2bf(acc[i][j][r]);
          }
        }
    } else {
#pragma unroll
      for (int i = 0; i < 4; ++i) {
        const int n0 = m0 + wm + i * 16 + lq * 4;
        const int bb = n0 >> 11, nl = n0 & 2047;
#pragma unroll
        for (int j = 0; j < 4; ++j) {
          const int cl = colbase + wn + j * 16 + lm;
          const int h = cl >> 6, d = cl & 63;
          s16x4 vp;
#pragma unroll
          for (int r = 0; r < 4; ++r) {
            const size_t idx = (((size_t)bb * H_ + h) * N_ + nl + r) * D_ + d;
            o0[(size_t)B_ * H_ * N_ * D_ + idx] = acc[i][j][r];
            vp[r] = (short)f2bf(acc[i][j][r]);
          }
          *(s16x4*)&oVt[(((size_t)bb * H_ + h) * D_ + d) * N_ + nl] = vp;
        }
      }
    }
  }
}

// =====================================================================
// Fused attention v3: i-tile 32, 512 thr (8 waves), j-step 32,
// SINGLE slot-reuse LDS buffer: Ssh[i][jt][16x20] holds scores, then E
// (in place, same wave), then P stored [g][j] in the same slot.
// attn_av: 43 KB LDS, 3 barriers/step -> 2 blocks/CU (VGPR<=128 via LB).
// Wave w: heads {2w,2w+1} for scores/AV; premix/postmix instances
// (i_loc = 4w + (ii&3), jt = ii>>2), ii=0..7.
// =====================================================================
#define SS_J 20
#define SLOT 320
#define SS_I 644   // 2*SLOT + 4 pad

// -------------------- pass 1: row sums l --------------------
__global__ __launch_bounds__(512, 4) void attn_l(const unsigned short* __restrict__ Qb,
                                                 const unsigned short* __restrict__ Kb,
                                                 const float* __restrict__ wpre,
                                                 const float* __restrict__ bpre,
                                                 float* __restrict__ l_glob) {
  __shared__ unsigned short Ssh[32 * SS_I];
  const int tid = threadIdx.x;
  const int wave = tid >> 6, lane = tid & 63;
  const int lm = lane & 15, lq = lane >> 4;
  const int b = blockIdx.z, jh = blockIdx.y;
  const int i0 = blockIdx.x * 32;
  const int j00 = jh * 1024;
  const int h0 = wave * 2;

  s16x8 aq[2][2][2];  // [hh][mi][ks]
#pragma unroll
  for (int hh = 0; hh < 2; ++hh)
#pragma unroll
    for (int mi = 0; mi < 2; ++mi)
#pragma unroll
      for (int ks = 0; ks < 2; ++ks)
        aq[hh][mi][ks] = *(const s16x8*)&Qb[(((size_t)(b * H_ + h0 + hh) * N_) + i0 + mi * 16 + lm) * D_ + ks * 32 + lq * 8];

  s16x8 apre;
#pragma unroll
  for (int t = 0; t < 8; ++t) apre[t] = 0;
  if (lq < 2)
#pragma unroll
    for (int t = 0; t < 8; ++t) apre[t] = (short)f2bf(wpre[lm * 16 + lq * 8 + t] * 0.125f);
  float bpre_r[4];
#pragma unroll
  for (int r = 0; r < 4; ++r) bpre_r[r] = bpre[lq * 4 + r];

  float lacc[4][4] = {};

  for (int js = 0; js < 1024; js += 32) {
    const int j0 = j00 + js;
    __syncthreads();  // prev premix reads done before score overwrite
#pragma unroll
    for (int jt = 0; jt < 2; ++jt) {
      f32x4 c[2][2];
#pragma unroll
      for (int hh = 0; hh < 2; ++hh) {
        const unsigned short* kp = &Kb[(((size_t)(b * H_ + h0 + hh) * N_) + j0 + jt * 16 + lm) * D_ + lq * 8];
        s16x8 b0 = *(const s16x8*)kp;
        s16x8 b1 = *(const s16x8*)(kp + 32);
#pragma unroll
        for (int mi = 0; mi < 2; ++mi) {
          f32x4 cc = {};
          cc = __builtin_amdgcn_mfma_f32_16x16x32_bf16(aq[hh][mi][0], b0, cc, 0, 0, 0);
          cc = __builtin_amdgcn_mfma_f32_16x16x32_bf16(aq[hh][mi][1], b1, cc, 0, 0, 0);
          c[hh][mi] = cc;
        }
      }
#pragma unroll
      for (int mi = 0; mi < 2; ++mi)
#pragma unroll
        for (int r = 0; r < 4; ++r) {
          unsigned int pk = (unsigned int)f2bf(c[0][mi][r]) | ((unsigned int)f2bf(c[1][mi][r]) << 16);
          *(unsigned int*)&Ssh[(mi * 16 + lq * 4 + r) * SS_I + jt * SLOT + lm * SS_J + h0] = pk;
        }
    }
    __syncthreads();
#pragma unroll
    for (int ii = 0; ii < 8; ++ii) {
      const int i_loc = wave * 4 + (ii & 3), jt = ii >> 2;
      const unsigned short* srow = &Ssh[i_loc * SS_I + jt * SLOT];
      s16x8 bs;
#pragma unroll
      for (int t = 0; t < 8; ++t) bs[t] = 0;
      if (lq < 2) {
        s16x4 p0 = *(const s16x4*)(srow + lm * SS_J + lq * 8);
        s16x4 p1 = *(const s16x4*)(srow + lm * SS_J + lq * 8 + 4);
        bs[0] = p0[0]; bs[1] = p0[1]; bs[2] = p0[2]; bs[3] = p0[3];
        bs[4] = p1[0]; bs[5] = p1[1]; bs[6] = p1[2]; bs[7] = p1[3];
      }
      f32x4 c = {};
      c = __builtin_amdgcn_mfma_f32_16x16x32_bf16(apre, bs, c, 0, 0, 0);
#pragma unroll
      for (int r = 0; r < 4; ++r) lacc[ii & 3][r] += __expf(c[r] + bpre_r[r]);
    }
  }
#pragma unroll
  for (int ig = 0; ig < 4; ++ig)
#pragma unroll
    for (int r = 0; r < 4; ++r) {
      float v = lacc[ig][r];
      v += __shfl_xor(v, 1); v += __shfl_xor(v, 2);
      v += __shfl_xor(v, 4); v += __shfl_xor(v, 8);
      if (lm == 0)
        atomicAdd(&l_glob[((size_t)b * N_ + i0 + wave * 4 + ig) * H_ + lq * 4 + r], v);
    }
}

// -------------------- pass 2: full pipeline + AV --------------------
__global__ __launch_bounds__(512, 4) void attn_av(const unsigned short* __restrict__ Qb,
                                                  const unsigned short* __restrict__ Kb,
                                                  const unsigned short* __restrict__ Vt,
                                                  const float* __restrict__ wpre,
                                                  const float* __restrict__ bpre,
                                                  const float* __restrict__ wpost,
                                                  const float* __restrict__ bpost,
                                                  const float* __restrict__ l_glob,
                                                  float* __restrict__ Opart) {
  __shared__ unsigned short Ssh[32 * SS_I];
  __shared__ float linv[512];
  const int tid = threadIdx.x;
  const int wave = tid >> 6, lane = tid & 63;
  const int lm = lane & 15, lq = lane >> 4;
  const int b = blockIdx.z, jh = blockIdx.y;
  const int i0 = blockIdx.x * 32;
  const int j00 = jh * 1024;
  const int h0 = wave * 2;
  float* Oout = Opart + (size_t)jh * ((size_t)B_ * N_ * 1024);

  linv[tid] = 1.0f / l_glob[((size_t)b * N_ + i0 + (tid >> 4)) * H_ + (tid & 15)];

  s16x8 aq[2][2][2];  // [hh][mi][ks]
#pragma unroll
  for (int hh = 0; hh < 2; ++hh)
#pragma unroll
    for (int mi = 0; mi < 2; ++mi)
#pragma unroll
      for (int ks = 0; ks < 2; ++ks)
        aq[hh][mi][ks] = *(const s16x8*)&Qb[(((size_t)(b * H_ + h0 + hh) * N_) + i0 + mi * 16 + lm) * D_ + ks * 32 + lq * 8];

  s16x8 apre, apost;
#pragma unroll
  for (int t = 0; t < 8; ++t) { apre[t] = 0; apost[t] = 0; }
  if (lq < 2)
#pragma unroll
    for (int t = 0; t < 8; ++t) {
      apre[t] = (short)f2bf(wpre[lm * 16 + lq * 8 + t] * 0.125f);
      apost[t] = (short)f2bf(wpost[lm * 16 + lq * 8 + t]);
    }
  float bpre_r[4], bpost_r[4];
#pragma unroll
  for (int r = 0; r < 4; ++r) {
    bpre_r[r] = bpre[lq * 4 + r];
    bpost_r[r] = bpost[lq * 4 + r];
  }

  f32x4 acc[2][2][4] = {};  // [g][mi][nd]

  for (int js = 0; js < 1024; js += 32) {
    const int j0 = j00 + js;
    __syncthreads();  // B0: prev AV slot reads done (also linv ready, iter 0)
    // ---- scores -> Ssh slots ----
#pragma unroll
    for (int jt = 0; jt < 2; ++jt) {
      f32x4 c[2][2];
#pragma unroll
      for (int hh = 0; hh < 2; ++hh) {
        const unsigned short* kp = &Kb[(((size_t)(b * H_ + h0 + hh) * N_) + j0 + jt * 16 + lm) * D_ + lq * 8];
        s16x8 b0 = *(const s16x8*)kp;
        s16x8 b1 = *(const s16x8*)(kp + 32);
#pragma unroll
        for (int mi = 0; mi < 2; ++mi) {
          f32x4 cc = {};
          cc = __builtin_amdgcn_mfma_f32_16x16x32_bf16(aq[hh][mi][0], b0, cc, 0, 0, 0);
          cc = __builtin_amdgcn_mfma_f32_16x16x32_bf16(aq[hh][mi][1], b1, cc, 0, 0, 0);
          c[hh][mi] = cc;
        }
      }
#pragma unroll
      for (int mi = 0; mi < 2; ++mi)
#pragma unroll
        for (int r = 0; r < 4; ++r) {
          unsigned int pk = (unsigned int)f2bf(c[0][mi][r]) | ((unsigned int)f2bf(c[1][mi][r]) << 16);
          *(unsigned int*)&Ssh[(mi * 16 + lq * 4 + r) * SS_I + jt * SLOT + lm * SS_J + h0] = pk;
        }
    }
    __syncthreads();  // B1: scores complete
    // ---- premix -> E (in place) -> postmix -> P (in place, [g][j]) ----
#pragma unroll
    for (int ii = 0; ii < 8; ++ii) {
      const int i_loc = wave * 4 + (ii & 3), jt = ii >> 2;
      unsigned short* srow = &Ssh[i_loc * SS_I + jt * SLOT];
      s16x8 bs;
#pragma unroll
      for (int t = 0; t < 8; ++t) bs[t] = 0;
      if (lq < 2) {
        s16x4 p0 = *(const s16x4*)(srow + lm * SS_J + lq * 8);
        s16x4 p1 = *(const s16x4*)(srow + lm * SS_J + lq * 8 + 4);
        bs[0] = p0[0]; bs[1] = p0[1]; bs[2] = p0[2]; bs[3] = p0[3];
        bs[4] = p1[0]; bs[5] = p1[1]; bs[6] = p1[2]; bs[7] = p1[3];
      }
      f32x4 c = {};
      c = __builtin_amdgcn_mfma_f32_16x16x32_bf16(apre, bs, c, 0, 0, 0);
      const float4 li = *(const float4*)&linv[i_loc * 16 + lq * 4];
      const float lif[4] = {li.x, li.y, li.z, li.w};
      s16x4 ep;
#pragma unroll
      for (int r = 0; r < 4; ++r)
        ep[r] = (short)f2bf(__expf(c[r] + bpre_r[r]) * lif[r]);
      *(s16x4*)(srow + lm * SS_J + lq * 4) = ep;  // E in place
      // postmix reads E of this same instance (same wave, DS in-order)
      s16x8 be;
#pragma unroll
      for (int t = 0; t < 8; ++t) be[t] = 0;
      if (lq < 2) {
        s16x4 q0 = *(const s16x4*)(srow + lm * SS_J + lq * 8);
        s16x4 q1 = *(const s16x4*)(srow + lm * SS_J + lq * 8 + 4);
        be[0] = q0[0]; be[1] = q0[1]; be[2] = q0[2]; be[3] = q0[3];
        be[4] = q1[0]; be[5] = q1[1]; be[6] = q1[2]; be[7] = q1[3];
      }
      f32x4 c2 = {};
      c2 = __builtin_amdgcn_mfma_f32_16x16x32_bf16(apost, be, c2, 0, 0, 0);
#pragma unroll
      for (int r = 0; r < 4; ++r)
        srow[(lq * 4 + r) * SS_J + lm] = f2bf(c2[r] + bpost_r[r]);  // P[g][j]
    }
    __syncthreads();  // B2: P complete
    // ---- AV: A = P from slots, B = Vt from global ----
#pragma unroll
    for (int g = 0; g < 2; ++g) {
      const int gg = h0 + g;
      s16x8 bv[4];
#pragma unroll
      for (int nd = 0; nd < 4; ++nd)
        bv[nd] = *(const s16x8*)&Vt[(((size_t)(b * H_ + gg) * D_) + nd * 16 + lm) * N_ + j0 + lq * 8];
#pragma unroll
      for (int mi = 0; mi < 2; ++mi) {
        const unsigned short* pbase =
            &Ssh[(mi * 16 + lm) * SS_I + (lq >> 1) * SLOT + gg * SS_J + (lq & 1) * 8];
        s16x4 a0 = *(const s16x4*)pbase;
        s16x4 a1 = *(const s16x4*)(pbase + 4);
        s16x8 ap;
        ap[0] = a0[0]; ap[1] = a0[1]; ap[2] = a0[2]; ap[3] = a0[3];
        ap[4] = a1[0]; ap[5] = a1[1]; ap[6] = a1[2]; ap[7] = a1[3];
#pragma unroll
        for (int nd = 0; nd < 4; ++nd)
          acc[g][mi][nd] = __builtin_amdgcn_mfma_f32_16x16x32_bf16(ap, bv[nd], acc[g][mi][nd], 0, 0, 0);
      }
    }
  }
#pragma unroll
  for (int g = 0; g < 2; ++g)
#pragma unroll
    for (int mi = 0; mi < 2; ++mi)
#pragma unroll
      for (int nd = 0; nd < 4; ++nd)
#pragma unroll
        for (int r = 0; r < 4; ++r)
          Oout[((size_t)b * N_ + i0 + mi * 16 + lq * 4 + r) * 1024 + (h0 + g) * 64 + nd * 16 + lm] = acc[g][mi][nd][r];
}

extern "C" void kernel_launch(void* const* d_in, const int* in_sizes, int n_in,
                              void* d_out, int out_size, void* d_ws,
                              size_t ws_size, hipStream_t stream) {
  (void)in_sizes; (void)n_in; (void)out_size; (void)ws_size;
  const float* x      = (const float*)d_in[0];
  const float* w_qkv  = (const float*)d_in[1];
  const float* w_out  = (const float*)d_in[2];
  const float* w_pre  = (const float*)d_in[3];
  const float* b_pre  = (const float*)d_in[4];
  const float* w_post = (const float*)d_in[5];
  const float* b_post = (const float*)d_in[6];

  float* out = (float*)d_out;                        // (B,N,F) fp32
  float* kv  = out + (size_t)B_ * N_ * F_;           // (2,B,H,N,D) fp32

  unsigned short* xb  = (unsigned short*)d_ws;            // 4096x1024
  unsigned short* wqb = xb + (size_t)4096 * 1024;         // 3072x1024 (permuted)
  unsigned short* wob = wqb + (size_t)3072 * 1024;        // 1024x1024
  unsigned short* Qb  = wob + (size_t)1024 * 1024;        // (B,H,N,D)
  unsigned short* Kb  = Qb + (size_t)B_ * H_ * N_ * D_;
  unsigned short* Vt  = Kb + (size_t)B_ * H_ * N_ * D_;   // (B,H,D,N)
  unsigned short* O1  = Vt + (size_t)B_ * H_ * N_ * D_;   // (B,N,1024) bf16
  float* l_glob = (float*)(O1 + (size_t)B_ * N_ * F_);    // (B,N,16) fp32
  float* Oh0 = l_glob + (size_t)B_ * N_ * H_;             // (B,N,1024) fp32
  float* Oh1 = Oh0 + (size_t)B_ * N_ * F_;                // (B,N,1024) fp32

  cvt_bf16<<<dim3(4096 * 1024 / 8 / 256), 256, 0, stream>>>(x, xb, 4096 * 1024 / 8);
  cvt_wqkv_perm<<<dim3(3072 * 128 / 256), 256, 0, stream>>>(w_qkv, wqb);
  cvt_bf16<<<dim3(1024 * 1024 / 8 / 256), 256, 0, stream>>>(w_out, wob, 1024 * 1024 / 8);
  hipMemsetAsync(l_glob, 0, (size_t)B_ * N_ * H_ * 4, stream);

  gemm_bf16<0><<<dim3(3072 / 128, 4096 / 128), 256, 0, stream>>>(xb, wqb, kv, Qb, Kb, Vt);

  attn_l<<<dim3(N_ / 32, 2, B_), 512, 0, stream>>>(Qb, Kb, w_pre, b_pre, l_glob);
  attn_av<<<dim3(N_ / 32, 2, B_), 512, 0, stream>>>(Qb, Kb, Vt, w_pre, b_pre, w_post, b_post,
                                                    l_glob, Oh0);

  cvt_sum<<<dim3(B_ * N_ * F_ / 4 / 256), 256, 0, stream>>>(Oh0, Oh1, O1);

  gemm_bf16<1><<<dim3(1024 / 128, 4096 / 128), 256, 0, stream>>>(O1, wob, out, nullptr, nullptr, nullptr);
}

// Round 8
// 455.873 us; speedup vs baseline: 1.4840x; 1.4840x over previous
//
#include <hip/hip_runtime.h>
#include <hip/hip_bf16.h>
#include <cstdint>
#include <cstddef>

#define B_ 2
#define N_ 2048
#define F_ 1024
#define H_ 16
#define D_ 64

typedef float f32x4 __attribute__((ext_vector_type(4)));
typedef short s16x8 __attribute__((ext_vector_type(8)));
typedef short s16x4 __attribute__((ext_vector_type(4)));

__device__ __forceinline__ unsigned short f2bf(float f) {
  union { __hip_bfloat16 h; unsigned short u; } c;
  c.h = __float2bfloat16(f);
  return c.u;
}
__device__ __forceinline__ float bf2f(unsigned short u) {
  union { __hip_bfloat16 h; unsigned short u; } c;
  c.u = u;
  return __bfloat162float(c.h);
}

// ---------------------------------------------------------------------
// fp32 -> bf16 bulk convert (8 elems/thread)
// ---------------------------------------------------------------------
__global__ __launch_bounds__(256) void cvt_bf16(const float* __restrict__ in,
                                                unsigned short* __restrict__ out,
                                                int n8) {
  const int t = blockIdx.x * 256 + threadIdx.x;
  if (t >= n8) return;
  const float4* p = (const float4*)in + (size_t)t * 2;
  float4 a = p[0], b = p[1];
  s16x8 o;
  o[0] = f2bf(a.x); o[1] = f2bf(a.y); o[2] = f2bf(a.z); o[3] = f2bf(a.w);
  o[4] = f2bf(b.x); o[5] = f2bf(b.y); o[6] = f2bf(b.z); o[7] = f2bf(b.w);
  *((s16x8*)out + t) = o;
}

// ---------------------------------------------------------------------
// w_qkv fp32 -> bf16 with row permutation: out row colp = c*1024 + h*64 + d
// ---------------------------------------------------------------------
__global__ __launch_bounds__(256) void cvt_wqkv_perm(const float* __restrict__ in,
                                                     unsigned short* __restrict__ out) {
  const int t = blockIdx.x * 256 + threadIdx.x;
  const int rowp = t >> 7;
  const int kk = (t & 127) * 8;
  const int c = rowp >> 10, rem = rowp & 1023;
  const int h = rem >> 6, d = rem & 63;
  const float* p = in + (size_t)(h * 192 + d * 3 + c) * 1024 + kk;
  float4 a = *(const float4*)p, b = *(const float4*)(p + 4);
  s16x8 o;
  o[0] = f2bf(a.x); o[1] = f2bf(a.y); o[2] = f2bf(a.z); o[3] = f2bf(a.w);
  o[4] = f2bf(b.x); o[5] = f2bf(b.y); o[6] = f2bf(b.z); o[7] = f2bf(b.w);
  *((s16x8*)&out[(size_t)rowp * 1024 + kk]) = o;
}

// ---------------------------------------------------------------------
// sum the four j-quarter fp32 O partials -> bf16 O1
// ---------------------------------------------------------------------
__global__ __launch_bounds__(256) void cvt_sum4(const float* __restrict__ a,
                                                unsigned short* __restrict__ out) {
  const int t = blockIdx.x * 256 + threadIdx.x;
  const size_t stride = (size_t)B_ * N_ * 1024 / 4;  // in float4 units
  float4 x0 = *((const float4*)a + t);
  float4 x1 = *((const float4*)a + stride + t);
  float4 x2 = *((const float4*)a + 2 * stride + t);
  float4 x3 = *((const float4*)a + 3 * stride + t);
  s16x4 o;
  o[0] = f2bf((x0.x + x1.x) + (x2.x + x3.x));
  o[1] = f2bf((x0.y + x1.y) + (x2.y + x3.y));
  o[2] = f2bf((x0.z + x1.z) + (x2.z + x3.z));
  o[3] = f2bf((x0.w + x1.w) + (x2.w + x3.w));
  *((s16x4*)out + t) = o;
}

// ---------------------------------------------------------------------
// MFMA GEMM (unchanged; passed rounds 4-7).
// ---------------------------------------------------------------------
template <int MODE>
__global__ __launch_bounds__(256) void gemm_bf16(const unsigned short* __restrict__ A,
                                                 const unsigned short* __restrict__ W,
                                                 float* __restrict__ o0,
                                                 unsigned short* __restrict__ oQ,
                                                 unsigned short* __restrict__ oK,
                                                 unsigned short* __restrict__ oVt) {
  __shared__ unsigned short As[128 * 72];
  __shared__ unsigned short Bs[128 * 72];
  const int m0 = blockIdx.y * 128, c0 = blockIdx.x * 128;
  const int tid = threadIdx.x;
  const int wave = tid >> 6, lane = tid & 63;
  const int wm = (wave & 1) * 64, wn = (wave >> 1) * 64;
  const int lm = lane & 15, lq = lane >> 4;
  f32x4 acc[4][4] = {};
  for (int k0 = 0; k0 < 1024; k0 += 64) {
#pragma unroll
    for (int it = 0; it < 4; ++it) {
      const int chunk = it * 256 + tid;
      const int row = chunk >> 3, kq = (chunk & 7) * 8;
      *(float4*)&As[row * 72 + kq] = *(const float4*)&A[(size_t)(m0 + row) * 1024 + k0 + kq];
      *(float4*)&Bs[row * 72 + kq] = *(const float4*)&W[(size_t)(c0 + row) * 1024 + k0 + kq];
    }
    __syncthreads();
#pragma unroll
    for (int ks = 0; ks < 2; ++ks) {
      s16x8 af[4], bfr[4];
#pragma unroll
      for (int i = 0; i < 4; ++i) {
        af[i] = *(const s16x8*)&As[(wm + i * 16 + lm) * 72 + ks * 32 + lq * 8];
        bfr[i] = *(const s16x8*)&Bs[(wn + i * 16 + lm) * 72 + ks * 32 + lq * 8];
      }
#pragma unroll
      for (int i = 0; i < 4; ++i)
#pragma unroll
        for (int j = 0; j < 4; ++j)
          acc[i][j] = __builtin_amdgcn_mfma_f32_16x16x32_bf16(af[i], bfr[j], acc[i][j], 0, 0, 0);
    }
    __syncthreads();
  }
  if (MODE == 1) {
#pragma unroll
    for (int i = 0; i < 4; ++i)
#pragma unroll
      for (int j = 0; j < 4; ++j)
#pragma unroll
        for (int r = 0; r < 4; ++r) {
          const int m = m0 + wm + i * 16 + lq * 4 + r;
          const int col = c0 + wn + j * 16 + lm;
          o0[(size_t)m * 1024 + col] = acc[i][j][r];
        }
  } else {
    const int cls = blockIdx.x >> 3;
    const int colbase = (blockIdx.x & 7) * 128;
    if (cls == 0) {
#pragma unroll
      for (int i = 0; i < 4; ++i)
#pragma unroll
        for (int j = 0; j < 4; ++j) {
          const int cl = colbase + wn + j * 16 + lm;
          const int h = cl >> 6, d = cl & 63;
#pragma unroll
          for (int r = 0; r < 4; ++r) {
            const int m = m0 + wm + i * 16 + lq * 4 + r;
            const int bb = m >> 11, n = m & 2047;
            oQ[(((size_t)bb * H_ + h) * N_ + n) * D_ + d] = f2bf(acc[i][j][r]);
          }
        }
    } else if (cls == 1) {
#pragma unroll
      for (int i = 0; i < 4; ++i)
#pragma unroll
        for (int j = 0; j < 4; ++j) {
          const int cl = colbase + wn + j * 16 + lm;
          const int h = cl >> 6, d = cl & 63;
#pragma unroll
          for (int r = 0; r < 4; ++r) {
            const int m = m0 + wm + i * 16 + lq * 4 + r;
            const int bb = m >> 11, n = m & 2047;
            const size_t idx = (((size_t)bb * H_ + h) * N_ + n) * D_ + d;
            o0[idx] = acc[i][j][r];
            oK[idx] = f2bf(acc[i][j][r]);
          }
        }
    } else {
#pragma unroll
      for (int i = 0; i < 4; ++i) {
        const int n0 = m0 + wm + i * 16 + lq * 4;
        const int bb = n0 >> 11, nl = n0 & 2047;
#pragma unroll
        for (int j = 0; j < 4; ++j) {
          const int cl = colbase + wn + j * 16 + lm;
          const int h = cl >> 6, d = cl & 63;
          s16x4 vp;
#pragma unroll
          for (int r = 0; r < 4; ++r) {
            const size_t idx = (((size_t)bb * H_ + h) * N_ + nl + r) * D_ + d;
            o0[(size_t)B_ * H_ * N_ * D_ + idx] = acc[i][j][r];
            vp[r] = (short)f2bf(acc[i][j][r]);
          }
          *(s16x4*)&oVt[(((size_t)bb * H_ + h) * D_ + d) * N_ + nl] = vp;
        }
      }
    }
  }
}

// =====================================================================
// Fused attention v4 = v3 structure, grid fixed for 2 blocks/CU:
// j split into 4 quarters (512 j each) -> grid 64 x 4 x 2 = 512 blocks;
// plain __launch_bounds__(512): compiler lands ~90-125 VGPR (no spill),
// 4 waves/SIMD; LDS 43.5 KB -> 2 blocks/CU co-resident.
// =====================================================================
#define SS_J 20
#define SLOT 320
#define SS_I 644   // 2*SLOT + 4 pad

// -------------------- pass 1: row sums l --------------------
__global__ __launch_bounds__(512) void attn_l(const unsigned short* __restrict__ Qb,
                                              const unsigned short* __restrict__ Kb,
                                              const float* __restrict__ wpre,
                                              const float* __restrict__ bpre,
                                              float* __restrict__ l_glob) {
  __shared__ unsigned short Ssh[32 * SS_I];
  const int tid = threadIdx.x;
  const int wave = tid >> 6, lane = tid & 63;
  const int lm = lane & 15, lq = lane >> 4;
  const int b = blockIdx.z, jh = blockIdx.y;
  const int i0 = blockIdx.x * 32;
  const int j00 = jh * 512;
  const int h0 = wave * 2;

  s16x8 aq[2][2][2];  // [hh][mi][ks]
#pragma unroll
  for (int hh = 0; hh < 2; ++hh)
#pragma unroll
    for (int mi = 0; mi < 2; ++mi)
#pragma unroll
      for (int ks = 0; ks < 2; ++ks)
        aq[hh][mi][ks] = *(const s16x8*)&Qb[(((size_t)(b * H_ + h0 + hh) * N_) + i0 + mi * 16 + lm) * D_ + ks * 32 + lq * 8];

  s16x8 apre;
#pragma unroll
  for (int t = 0; t < 8; ++t) apre[t] = 0;
  if (lq < 2)
#pragma unroll
    for (int t = 0; t < 8; ++t) apre[t] = (short)f2bf(wpre[lm * 16 + lq * 8 + t] * 0.125f);
  float bpre_r[4];
#pragma unroll
  for (int r = 0; r < 4; ++r) bpre_r[r] = bpre[lq * 4 + r];

  float lacc[4][4] = {};

  for (int js = 0; js < 512; js += 32) {
    const int j0 = j00 + js;
    __syncthreads();  // prev premix reads done before score overwrite
#pragma unroll
    for (int jt = 0; jt < 2; ++jt) {
      f32x4 c[2][2];
#pragma unroll
      for (int hh = 0; hh < 2; ++hh) {
        const unsigned short* kp = &Kb[(((size_t)(b * H_ + h0 + hh) * N_) + j0 + jt * 16 + lm) * D_ + lq * 8];
        s16x8 b0 = *(const s16x8*)kp;
        s16x8 b1 = *(const s16x8*)(kp + 32);
#pragma unroll
        for (int mi = 0; mi < 2; ++mi) {
          f32x4 cc = {};
          cc = __builtin_amdgcn_mfma_f32_16x16x32_bf16(aq[hh][mi][0], b0, cc, 0, 0, 0);
          cc = __builtin_amdgcn_mfma_f32_16x16x32_bf16(aq[hh][mi][1], b1, cc, 0, 0, 0);
          c[hh][mi] = cc;
        }
      }
#pragma unroll
      for (int mi = 0; mi < 2; ++mi)
#pragma unroll
        for (int r = 0; r < 4; ++r) {
          unsigned int pk = (unsigned int)f2bf(c[0][mi][r]) | ((unsigned int)f2bf(c[1][mi][r]) << 16);
          *(unsigned int*)&Ssh[(mi * 16 + lq * 4 + r) * SS_I + jt * SLOT + lm * SS_J + h0] = pk;
        }
    }
    __syncthreads();
#pragma unroll
    for (int ii = 0; ii < 8; ++ii) {
      const int i_loc = wave * 4 + (ii & 3), jt = ii >> 2;
      const unsigned short* srow = &Ssh[i_loc * SS_I + jt * SLOT];
      s16x8 bs;
#pragma unroll
      for (int t = 0; t < 8; ++t) bs[t] = 0;
      if (lq < 2) {
        s16x4 p0 = *(const s16x4*)(srow + lm * SS_J + lq * 8);
        s16x4 p1 = *(const s16x4*)(srow + lm * SS_J + lq * 8 + 4);
        bs[0] = p0[0]; bs[1] = p0[1]; bs[2] = p0[2]; bs[3] = p0[3];
        bs[4] = p1[0]; bs[5] = p1[1]; bs[6] = p1[2]; bs[7] = p1[3];
      }
      f32x4 c = {};
      c = __builtin_amdgcn_mfma_f32_16x16x32_bf16(apre, bs, c, 0, 0, 0);
#pragma unroll
      for (int r = 0; r < 4; ++r) lacc[ii & 3][r] += __expf(c[r] + bpre_r[r]);
    }
  }
#pragma unroll
  for (int ig = 0; ig < 4; ++ig)
#pragma unroll
    for (int r = 0; r < 4; ++r) {
      float v = lacc[ig][r];
      v += __shfl_xor(v, 1); v += __shfl_xor(v, 2);
      v += __shfl_xor(v, 4); v += __shfl_xor(v, 8);
      if (lm == 0)
        atomicAdd(&l_glob[((size_t)b * N_ + i0 + wave * 4 + ig) * H_ + lq * 4 + r], v);
    }
}

// -------------------- pass 2: full pipeline + AV --------------------
__global__ __launch_bounds__(512) void attn_av(const unsigned short* __restrict__ Qb,
                                               const unsigned short* __restrict__ Kb,
                                               const unsigned short* __restrict__ Vt,
                                               const float* __restrict__ wpre,
                                               const float* __restrict__ bpre,
                                               const float* __restrict__ wpost,
                                               const float* __restrict__ bpost,
                                               const float* __restrict__ l_glob,
                                               float* __restrict__ Opart) {
  __shared__ unsigned short Ssh[32 * SS_I];
  __shared__ float linv[512];
  const int tid = threadIdx.x;
  const int wave = tid >> 6, lane = tid & 63;
  const int lm = lane & 15, lq = lane >> 4;
  const int b = blockIdx.z, jh = blockIdx.y;
  const int i0 = blockIdx.x * 32;
  const int j00 = jh * 512;
  const int h0 = wave * 2;
  float* Oout = Opart + (size_t)jh * ((size_t)B_ * N_ * 1024);

  linv[tid] = 1.0f / l_glob[((size_t)b * N_ + i0 + (tid >> 4)) * H_ + (tid & 15)];

  s16x8 aq[2][2][2];  // [hh][mi][ks]
#pragma unroll
  for (int hh = 0; hh < 2; ++hh)
#pragma unroll
    for (int mi = 0; mi < 2; ++mi)
#pragma unroll
      for (int ks = 0; ks < 2; ++ks)
        aq[hh][mi][ks] = *(const s16x8*)&Qb[(((size_t)(b * H_ + h0 + hh) * N_) + i0 + mi * 16 + lm) * D_ + ks * 32 + lq * 8];

  s16x8 apre, apost;
#pragma unroll
  for (int t = 0; t < 8; ++t) { apre[t] = 0; apost[t] = 0; }
  if (lq < 2)
#pragma unroll
    for (int t = 0; t < 8; ++t) {
      apre[t] = (short)f2bf(wpre[lm * 16 + lq * 8 + t] * 0.125f);
      apost[t] = (short)f2bf(wpost[lm * 16 + lq * 8 + t]);
    }
  float bpre_r[4], bpost_r[4];
#pragma unroll
  for (int r = 0; r < 4; ++r) {
    bpre_r[r] = bpre[lq * 4 + r];
    bpost_r[r] = bpost[lq * 4 + r];
  }

  f32x4 acc[2][2][4] = {};  // [g][mi][nd]

  for (int js = 0; js < 512; js += 32) {
    const int j0 = j00 + js;
    __syncthreads();  // B0: prev AV slot reads done (also linv ready, iter 0)
    // ---- scores -> Ssh slots ----
#pragma unroll
    for (int jt = 0; jt < 2; ++jt) {
      f32x4 c[2][2];
#pragma unroll
      for (int hh = 0; hh < 2; ++hh) {
        const unsigned short* kp = &Kb[(((size_t)(b * H_ + h0 + hh) * N_) + j0 + jt * 16 + lm) * D_ + lq * 8];
        s16x8 b0 = *(const s16x8*)kp;
        s16x8 b1 = *(const s16x8*)(kp + 32);
#pragma unroll
        for (int mi = 0; mi < 2; ++mi) {
          f32x4 cc = {};
          cc = __builtin_amdgcn_mfma_f32_16x16x32_bf16(aq[hh][mi][0], b0, cc, 0, 0, 0);
          cc = __builtin_amdgcn_mfma_f32_16x16x32_bf16(aq[hh][mi][1], b1, cc, 0, 0, 0);
          c[hh][mi] = cc;
        }
      }
#pragma unroll
      for (int mi = 0; mi < 2; ++mi)
#pragma unroll
        for (int r = 0; r < 4; ++r) {
          unsigned int pk = (unsigned int)f2bf(c[0][mi][r]) | ((unsigned int)f2bf(c[1][mi][r]) << 16);
          *(unsigned int*)&Ssh[(mi * 16 + lq * 4 + r) * SS_I + jt * SLOT + lm * SS_J + h0] = pk;
        }
    }
    __syncthreads();  // B1: scores complete
    // ---- premix -> E (in place) -> postmix -> P (in place, [g][j]) ----
#pragma unroll
    for (int ii = 0; ii < 8; ++ii) {
      const int i_loc = wave * 4 + (ii & 3), jt = ii >> 2;
      unsigned short* srow = &Ssh[i_loc * SS_I + jt * SLOT];
      s16x8 bs;
#pragma unroll
      for (int t = 0; t < 8; ++t) bs[t] = 0;
      if (lq < 2) {
        s16x4 p0 = *(const s16x4*)(srow + lm * SS_J + lq * 8);
        s16x4 p1 = *(const s16x4*)(srow + lm * SS_J + lq * 8 + 4);
        bs[0] = p0[0]; bs[1] = p0[1]; bs[2] = p0[2]; bs[3] = p0[3];
        bs[4] = p1[0]; bs[5] = p1[1]; bs[6] = p1[2]; bs[7] = p1[3];
      }
      f32x4 c = {};
      c = __builtin_amdgcn_mfma_f32_16x16x32_bf16(apre, bs, c, 0, 0, 0);
      const float4 li = *(const float4*)&linv[i_loc * 16 + lq * 4];
      const float lif[4] = {li.x, li.y, li.z, li.w};
      s16x4 ep;
#pragma unroll
      for (int r = 0; r < 4; ++r)
        ep[r] = (short)f2bf(__expf(c[r] + bpre_r[r]) * lif[r]);
      *(s16x4*)(srow + lm * SS_J + lq * 4) = ep;  // E in place
      // postmix reads E of this same instance (same wave, DS in-order)
      s16x8 be;
#pragma unroll
      for (int t = 0; t < 8; ++t) be[t] = 0;
      if (lq < 2) {
        s16x4 q0 = *(const s16x4*)(srow + lm * SS_J + lq * 8);
        s16x4 q1 = *(const s16x4*)(srow + lm * SS_J + lq * 8 + 4);
        be[0] = q0[0]; be[1] = q0[1]; be[2] = q0[2]; be[3] = q0[3];
        be[4] = q1[0]; be[5] = q1[1]; be[6] = q1[2]; be[7] = q1[3];
      }
      f32x4 c2 = {};
      c2 = __builtin_amdgcn_mfma_f32_16x16x32_bf16(apost, be, c2, 0, 0, 0);
#pragma unroll
      for (int r = 0; r < 4; ++r)
        srow[(lq * 4 + r) * SS_J + lm] = f2bf(c2[r] + bpost_r[r]);  // P[g][j]
    }
    __syncthreads();  // B2: P complete
    // ---- AV: A = P from slots, B = Vt from global ----
#pragma unroll
    for (int g = 0; g < 2; ++g) {
      const int gg = h0 + g;
      s16x8 bv[4];
#pragma unroll
      for (int nd = 0; nd < 4; ++nd)
        bv[nd] = *(const s16x8*)&Vt[(((size_t)(b * H_ + gg) * D_) + nd * 16 + lm) * N_ + j0 + lq * 8];
#pragma unroll
      for (int mi = 0; mi < 2; ++mi) {
        const unsigned short* pbase =
            &Ssh[(mi * 16 + lm) * SS_I + (lq >> 1) * SLOT + gg * SS_J + (lq & 1) * 8];
        s16x4 a0 = *(const s16x4*)pbase;
        s16x4 a1 = *(const s16x4*)(pbase + 4);
        s16x8 ap;
        ap[0] = a0[0]; ap[1] = a0[1]; ap[2] = a0[2]; ap[3] = a0[3];
        ap[4] = a1[0]; ap[5] = a1[1]; ap[6] = a1[2]; ap[7] = a1[3];
#pragma unroll
        for (int nd = 0; nd < 4; ++nd)
          acc[g][mi][nd] = __builtin_amdgcn_mfma_f32_16x16x32_bf16(ap, bv[nd], acc[g][mi][nd], 0, 0, 0);
      }
    }
  }
#pragma unroll
  for (int g = 0; g < 2; ++g)
#pragma unroll
    for (int mi = 0; mi < 2; ++mi)
#pragma unroll
      for (int nd = 0; nd < 4; ++nd)
#pragma unroll
        for (int r = 0; r < 4; ++r)
          Oout[((size_t)b * N_ + i0 + mi * 16 + lq * 4 + r) * 1024 + (h0 + g) * 64 + nd * 16 + lm] = acc[g][mi][nd][r];
}

extern "C" void kernel_launch(void* const* d_in, const int* in_sizes, int n_in,
                              void* d_out, int out_size, void* d_ws,
                              size_t ws_size, hipStream_t stream) {
  (void)in_sizes; (void)n_in; (void)out_size; (void)ws_size;
  const float* x      = (const float*)d_in[0];
  const float* w_qkv  = (const float*)d_in[1];
  const float* w_out  = (const float*)d_in[2];
  const float* w_pre  = (const float*)d_in[3];
  const float* b_pre  = (const float*)d_in[4];
  const float* w_post = (const float*)d_in[5];
  const float* b_post = (const float*)d_in[6];

  float* out = (float*)d_out;                        // (B,N,F) fp32
  float* kv  = out + (size_t)B_ * N_ * F_;           // (2,B,H,N,D) fp32

  unsigned short* xb  = (unsigned short*)d_ws;            // 4096x1024
  unsigned short* wqb = xb + (size_t)4096 * 1024;         // 3072x1024 (permuted)
  unsigned short* wob = wqb + (size_t)3072 * 1024;        // 1024x1024
  unsigned short* Qb  = wob + (size_t)1024 * 1024;        // (B,H,N,D)
  unsigned short* Kb  = Qb + (size_t)B_ * H_ * N_ * D_;
  unsigned short* Vt  = Kb + (size_t)B_ * H_ * N_ * D_;   // (B,H,D,N)
  unsigned short* O1  = Vt + (size_t)B_ * H_ * N_ * D_;   // (B,N,1024) bf16
  float* l_glob = (float*)(O1 + (size_t)B_ * N_ * F_);    // (B,N,16) fp32
  float* Oh = l_glob + (size_t)B_ * N_ * H_;              // 4 x (B,N,1024) fp32

  cvt_bf16<<<dim3(4096 * 1024 / 8 / 256), 256, 0, stream>>>(x, xb, 4096 * 1024 / 8);
  cvt_wqkv_perm<<<dim3(3072 * 128 / 256), 256, 0, stream>>>(w_qkv, wqb);
  cvt_bf16<<<dim3(1024 * 1024 / 8 / 256), 256, 0, stream>>>(w_out, wob, 1024 * 1024 / 8);
  hipMemsetAsync(l_glob, 0, (size_t)B_ * N_ * H_ * 4, stream);

  gemm_bf16<0><<<dim3(3072 / 128, 4096 / 128), 256, 0, stream>>>(xb, wqb, kv, Qb, Kb, Vt);

  attn_l<<<dim3(N_ / 32, 4, B_), 512, 0, stream>>>(Qb, Kb, w_pre, b_pre, l_glob);
  attn_av<<<dim3(N_ / 32, 4, B_), 512, 0, stream>>>(Qb, Kb, Vt, w_pre, b_pre, w_post, b_post,
                                                    l_glob, Oh);

  cvt_sum4<<<dim3(B_ * N_ * F_ / 4 / 256), 256, 0, stream>>>(Oh, O1);

  gemm_bf16<1><<<dim3(1024 / 128, 4096 / 128), 256, 0, stream>>>(O1, wob, out, nullptr, nullptr, nullptr);
}

// Round 9
// 439.538 us; speedup vs baseline: 1.5392x; 1.0372x over previous
//
#include <hip/hip_runtime.h>
#include <hip/hip_bf16.h>
#include <cstdint>
#include <cstddef>

#define B_ 2
#define N_ 2048
#define F_ 1024
#define H_ 16
#define D_ 64

typedef float f32x4 __attribute__((ext_vector_type(4)));
typedef short s16x8 __attribute__((ext_vector_type(8)));
typedef short s16x4 __attribute__((ext_vector_type(4)));

__device__ __forceinline__ unsigned short f2bf(float f) {
  union { __hip_bfloat16 h; unsigned short u; } c;
  c.h = __float2bfloat16(f);
  return c.u;
}
__device__ __forceinline__ float bf2f(unsigned short u) {
  union { __hip_bfloat16 h; unsigned short u; } c;
  c.u = u;
  return __bfloat162float(c.h);
}

// ---------------------------------------------------------------------
// fp32 -> bf16 bulk convert (8 elems/thread)
// ---------------------------------------------------------------------
__global__ __launch_bounds__(256) void cvt_bf16(const float* __restrict__ in,
                                                unsigned short* __restrict__ out,
                                                int n8) {
  const int t = blockIdx.x * 256 + threadIdx.x;
  if (t >= n8) return;
  const float4* p = (const float4*)in + (size_t)t * 2;
  float4 a = p[0], b = p[1];
  s16x8 o;
  o[0] = f2bf(a.x); o[1] = f2bf(a.y); o[2] = f2bf(a.z); o[3] = f2bf(a.w);
  o[4] = f2bf(b.x); o[5] = f2bf(b.y); o[6] = f2bf(b.z); o[7] = f2bf(b.w);
  *((s16x8*)out + t) = o;
}

// ---------------------------------------------------------------------
// w_qkv fp32 -> bf16 with row permutation: out row colp = c*1024 + h*64 + d
// ---------------------------------------------------------------------
__global__ __launch_bounds__(256) void cvt_wqkv_perm(const float* __restrict__ in,
                                                     unsigned short* __restrict__ out) {
  const int t = blockIdx.x * 256 + threadIdx.x;
  const int rowp = t >> 7;
  const int kk = (t & 127) * 8;
  const int c = rowp >> 10, rem = rowp & 1023;
  const int h = rem >> 6, d = rem & 63;
  const float* p = in + (size_t)(h * 192 + d * 3 + c) * 1024 + kk;
  float4 a = *(const float4*)p, b = *(const float4*)(p + 4);
  s16x8 o;
  o[0] = f2bf(a.x); o[1] = f2bf(a.y); o[2] = f2bf(a.z); o[3] = f2bf(a.w);
  o[4] = f2bf(b.x); o[5] = f2bf(b.y); o[6] = f2bf(b.z); o[7] = f2bf(b.w);
  *((s16x8*)&out[(size_t)rowp * 1024 + kk]) = o;
}

// ---------------------------------------------------------------------
// sum the four j-quarter fp32 O partials -> bf16 O1
// ---------------------------------------------------------------------
__global__ __launch_bounds__(256) void cvt_sum4(const float* __restrict__ a,
                                                unsigned short* __restrict__ out) {
  const int t = blockIdx.x * 256 + threadIdx.x;
  const size_t stride = (size_t)B_ * N_ * 1024 / 4;  // in float4 units
  float4 x0 = *((const float4*)a + t);
  float4 x1 = *((const float4*)a + stride + t);
  float4 x2 = *((const float4*)a + 2 * stride + t);
  float4 x3 = *((const float4*)a + 3 * stride + t);
  s16x4 o;
  o[0] = f2bf((x0.x + x1.x) + (x2.x + x3.x));
  o[1] = f2bf((x0.y + x1.y) + (x2.y + x3.y));
  o[2] = f2bf((x0.z + x1.z) + (x2.z + x3.z));
  o[3] = f2bf((x0.w + x1.w) + (x2.w + x3.w));
  *((s16x4*)out + t) = o;
}

// ---------------------------------------------------------------------
// MFMA GEMM (unchanged; passed rounds 4-8).
// ---------------------------------------------------------------------
template <int MODE>
__global__ __launch_bounds__(256) void gemm_bf16(const unsigned short* __restrict__ A,
                                                 const unsigned short* __restrict__ W,
                                                 float* __restrict__ o0,
                                                 unsigned short* __restrict__ oQ,
                                                 unsigned short* __restrict__ oK,
                                                 unsigned short* __restrict__ oVt) {
  __shared__ unsigned short As[128 * 72];
  __shared__ unsigned short Bs[128 * 72];
  const int m0 = blockIdx.y * 128, c0 = blockIdx.x * 128;
  const int tid = threadIdx.x;
  const int wave = tid >> 6, lane = tid & 63;
  const int wm = (wave & 1) * 64, wn = (wave >> 1) * 64;
  const int lm = lane & 15, lq = lane >> 4;
  f32x4 acc[4][4] = {};
  for (int k0 = 0; k0 < 1024; k0 += 64) {
#pragma unroll
    for (int it = 0; it < 4; ++it) {
      const int chunk = it * 256 + tid;
      const int row = chunk >> 3, kq = (chunk & 7) * 8;
      *(float4*)&As[row * 72 + kq] = *(const float4*)&A[(size_t)(m0 + row) * 1024 + k0 + kq];
      *(float4*)&Bs[row * 72 + kq] = *(const float4*)&W[(size_t)(c0 + row) * 1024 + k0 + kq];
    }
    __syncthreads();
#pragma unroll
    for (int ks = 0; ks < 2; ++ks) {
      s16x8 af[4], bfr[4];
#pragma unroll
      for (int i = 0; i < 4; ++i) {
        af[i] = *(const s16x8*)&As[(wm + i * 16 + lm) * 72 + ks * 32 + lq * 8];
        bfr[i] = *(const s16x8*)&Bs[(wn + i * 16 + lm) * 72 + ks * 32 + lq * 8];
      }
#pragma unroll
      for (int i = 0; i < 4; ++i)
#pragma unroll
        for (int j = 0; j < 4; ++j)
          acc[i][j] = __builtin_amdgcn_mfma_f32_16x16x32_bf16(af[i], bfr[j], acc[i][j], 0, 0, 0);
    }
    __syncthreads();
  }
  if (MODE == 1) {
#pragma unroll
    for (int i = 0; i < 4; ++i)
#pragma unroll
      for (int j = 0; j < 4; ++j)
#pragma unroll
        for (int r = 0; r < 4; ++r) {
          const int m = m0 + wm + i * 16 + lq * 4 + r;
          const int col = c0 + wn + j * 16 + lm;
          o0[(size_t)m * 1024 + col] = acc[i][j][r];
        }
  } else {
    const int cls = blockIdx.x >> 3;
    const int colbase = (blockIdx.x & 7) * 128;
    if (cls == 0) {
#pragma unroll
      for (int i = 0; i < 4; ++i)
#pragma unroll
        for (int j = 0; j < 4; ++j) {
          const int cl = colbase + wn + j * 16 + lm;
          const int h = cl >> 6, d = cl & 63;
#pragma unroll
          for (int r = 0; r < 4; ++r) {
            const int m = m0 + wm + i * 16 + lq * 4 + r;
            const int bb = m >> 11, n = m & 2047;
            oQ[(((size_t)bb * H_ + h) * N_ + n) * D_ + d] = f2bf(acc[i][j][r]);
          }
        }
    } else if (cls == 1) {
#pragma unroll
      for (int i = 0; i < 4; ++i)
#pragma unroll
        for (int j = 0; j < 4; ++j) {
          const int cl = colbase + wn + j * 16 + lm;
          const int h = cl >> 6, d = cl & 63;
#pragma unroll
          for (int r = 0; r < 4; ++r) {
            const int m = m0 + wm + i * 16 + lq * 4 + r;
            const int bb = m >> 11, n = m & 2047;
            const size_t idx = (((size_t)bb * H_ + h) * N_ + n) * D_ + d;
            o0[idx] = acc[i][j][r];
            oK[idx] = f2bf(acc[i][j][r]);
          }
        }
    } else {
#pragma unroll
      for (int i = 0; i < 4; ++i) {
        const int n0 = m0 + wm + i * 16 + lq * 4;
        const int bb = n0 >> 11, nl = n0 & 2047;
#pragma unroll
        for (int j = 0; j < 4; ++j) {
          const int cl = colbase + wn + j * 16 + lm;
          const int h = cl >> 6, d = cl & 63;
          s16x4 vp;
#pragma unroll
          for (int r = 0; r < 4; ++r) {
            const size_t idx = (((size_t)bb * H_ + h) * N_ + nl + r) * D_ + d;
            o0[(size_t)B_ * H_ * N_ * D_ + idx] = acc[i][j][r];
            vp[r] = (short)f2bf(acc[i][j][r]);
          }
          *(s16x4*)&oVt[(((size_t)bb * H_ + h) * D_ + d) * N_ + nl] = vp;
        }
      }
    }
  }
}

// =====================================================================
// Fused attention v5: i-tile 32, j-step 32, 512 thr (8 waves), grid
// (64, 4 j-quarters, B). 2 barriers/step. Separate P buffer + SWAPPED
// postmix MFMA (A=E, B=wpost) -> output row=j, col=g' -> b64 P writes
// and b64 AV A-frag reads (no b16 scatters anywhere).
// S slot [i][jt][j16][h16] stride SS_J=20; E overwrites S in place
// (same-wave in-order DS). P[g][i][j]: PS_J=36, PS_G=1156.
// LDS: S 41.2 KB + P 36.1 KB + linv 2 KB = 80.3 KB.
// =====================================================================
#define SS_J 20
#define SLOT 320
#define SS_I 644   // 2*SLOT + 4 pad
#define PS_J 36
#define PS_G 1156  // 32*36 + 4

// -------------------- pass 1: row sums l (round-8 structure) ---------
__global__ __launch_bounds__(512) void attn_l(const unsigned short* __restrict__ Qb,
                                              const unsigned short* __restrict__ Kb,
                                              const float* __restrict__ wpre,
                                              const float* __restrict__ bpre,
                                              float* __restrict__ l_glob) {
  __shared__ unsigned short Ssh[32 * SS_I];
  const int tid = threadIdx.x;
  const int wave = tid >> 6, lane = tid & 63;
  const int lm = lane & 15, lq = lane >> 4;
  const int b = blockIdx.z, jh = blockIdx.y;
  const int i0 = blockIdx.x * 32;
  const int j00 = jh * 512;
  const int h0 = wave * 2;

  s16x8 aq[2][2][2];  // [hh][mi][ks]
#pragma unroll
  for (int hh = 0; hh < 2; ++hh)
#pragma unroll
    for (int mi = 0; mi < 2; ++mi)
#pragma unroll
      for (int ks = 0; ks < 2; ++ks)
        aq[hh][mi][ks] = *(const s16x8*)&Qb[(((size_t)(b * H_ + h0 + hh) * N_) + i0 + mi * 16 + lm) * D_ + ks * 32 + lq * 8];

  s16x8 apre;
#pragma unroll
  for (int t = 0; t < 8; ++t) apre[t] = 0;
  if (lq < 2)
#pragma unroll
    for (int t = 0; t < 8; ++t) apre[t] = (short)f2bf(wpre[lm * 16 + lq * 8 + t] * 0.125f);
  float bpre_r[4];
#pragma unroll
  for (int r = 0; r < 4; ++r) bpre_r[r] = bpre[lq * 4 + r];

  float lacc[4][4] = {};

  for (int js = 0; js < 512; js += 32) {
    const int j0 = j00 + js;
    __syncthreads();  // prev premix reads done before score overwrite
#pragma unroll
    for (int jt = 0; jt < 2; ++jt) {
      f32x4 c[2][2];
#pragma unroll
      for (int hh = 0; hh < 2; ++hh) {
        const unsigned short* kp = &Kb[(((size_t)(b * H_ + h0 + hh) * N_) + j0 + jt * 16 + lm) * D_ + lq * 8];
        s16x8 b0 = *(const s16x8*)kp;
        s16x8 b1 = *(const s16x8*)(kp + 32);
#pragma unroll
        for (int mi = 0; mi < 2; ++mi) {
          f32x4 cc = {};
          cc = __builtin_amdgcn_mfma_f32_16x16x32_bf16(aq[hh][mi][0], b0, cc, 0, 0, 0);
          cc = __builtin_amdgcn_mfma_f32_16x16x32_bf16(aq[hh][mi][1], b1, cc, 0, 0, 0);
          c[hh][mi] = cc;
        }
      }
#pragma unroll
      for (int mi = 0; mi < 2; ++mi)
#pragma unroll
        for (int r = 0; r < 4; ++r) {
          unsigned int pk = (unsigned int)f2bf(c[0][mi][r]) | ((unsigned int)f2bf(c[1][mi][r]) << 16);
          *(unsigned int*)&Ssh[(mi * 16 + lq * 4 + r) * SS_I + jt * SLOT + lm * SS_J + h0] = pk;
        }
    }
    __syncthreads();
#pragma unroll
    for (int ii = 0; ii < 8; ++ii) {
      const int i_loc = wave * 4 + (ii & 3), jt = ii >> 2;
      const unsigned short* srow = &Ssh[i_loc * SS_I + jt * SLOT];
      s16x8 bs;
#pragma unroll
      for (int t = 0; t < 8; ++t) bs[t] = 0;
      if (lq < 2) {
        s16x4 p0 = *(const s16x4*)(srow + lm * SS_J + lq * 8);
        s16x4 p1 = *(const s16x4*)(srow + lm * SS_J + lq * 8 + 4);
        bs[0] = p0[0]; bs[1] = p0[1]; bs[2] = p0[2]; bs[3] = p0[3];
        bs[4] = p1[0]; bs[5] = p1[1]; bs[6] = p1[2]; bs[7] = p1[3];
      }
      f32x4 c = {};
      c = __builtin_amdgcn_mfma_f32_16x16x32_bf16(apre, bs, c, 0, 0, 0);
#pragma unroll
      for (int r = 0; r < 4; ++r) lacc[ii & 3][r] += __expf(c[r] + bpre_r[r]);
    }
  }
#pragma unroll
  for (int ig = 0; ig < 4; ++ig)
#pragma unroll
    for (int r = 0; r < 4; ++r) {
      float v = lacc[ig][r];
      v += __shfl_xor(v, 1); v += __shfl_xor(v, 2);
      v += __shfl_xor(v, 4); v += __shfl_xor(v, 8);
      if (lm == 0)
        atomicAdd(&l_glob[((size_t)b * N_ + i0 + wave * 4 + ig) * H_ + lq * 4 + r], v);
    }
}

// -------------------- pass 2: full pipeline + AV --------------------
__global__ __launch_bounds__(512) void attn_av(const unsigned short* __restrict__ Qb,
                                               const unsigned short* __restrict__ Kb,
                                               const unsigned short* __restrict__ Vt,
                                               const float* __restrict__ wpre,
                                               const float* __restrict__ bpre,
                                               const float* __restrict__ wpost,
                                               const float* __restrict__ bpost,
                                               const float* __restrict__ l_glob,
                                               float* __restrict__ Opart) {
  __shared__ unsigned short Ssh[32 * SS_I];
  __shared__ unsigned short Psh[16 * PS_G];
  __shared__ float linv[512];
  const int tid = threadIdx.x;
  const int wave = tid >> 6, lane = tid & 63;
  const int lm = lane & 15, lq = lane >> 4;
  const int b = blockIdx.z, jh = blockIdx.y;
  const int i0 = blockIdx.x * 32;
  const int j00 = jh * 512;
  const int h0 = wave * 2;
  float* Oout = Opart + (size_t)jh * ((size_t)B_ * N_ * 1024);

  linv[tid] = 1.0f / l_glob[((size_t)b * N_ + i0 + (tid >> 4)) * H_ + (tid & 15)];

  s16x8 aq[2][2][2];  // [hh][mi][ks]
#pragma unroll
  for (int hh = 0; hh < 2; ++hh)
#pragma unroll
    for (int mi = 0; mi < 2; ++mi)
#pragma unroll
      for (int ks = 0; ks < 2; ++ks)
        aq[hh][mi][ks] = *(const s16x8*)&Qb[(((size_t)(b * H_ + h0 + hh) * N_) + i0 + mi * 16 + lm) * D_ + ks * 32 + lq * 8];

  s16x8 apre, apost;
#pragma unroll
  for (int t = 0; t < 8; ++t) { apre[t] = 0; apost[t] = 0; }
  if (lq < 2)
#pragma unroll
    for (int t = 0; t < 8; ++t) {
      apre[t] = (short)f2bf(wpre[lm * 16 + lq * 8 + t] * 0.125f);
      apost[t] = (short)f2bf(wpost[lm * 16 + lq * 8 + t]);
    }
  float bpre_r[4];
#pragma unroll
  for (int r = 0; r < 4; ++r) bpre_r[r] = bpre[lq * 4 + r];
  const float bpost_lm = bpost[lm];  // postmix output col = g' = lm

  f32x4 acc[2][2][4] = {};  // [g][mi][nd]

  for (int js = 0; js < 512; js += 32) {
    const int j0 = j00 + js;
    // ---- scores -> Ssh slots (prev premix reads finished before prev B2;
    //      prev AV touches only Psh/global) ----
#pragma unroll
    for (int jt = 0; jt < 2; ++jt) {
      f32x4 c[2][2];
#pragma unroll
      for (int hh = 0; hh < 2; ++hh) {
        const unsigned short* kp = &Kb[(((size_t)(b * H_ + h0 + hh) * N_) + j0 + jt * 16 + lm) * D_ + lq * 8];
        s16x8 b0 = *(const s16x8*)kp;
        s16x8 b1 = *(const s16x8*)(kp + 32);
#pragma unroll
        for (int mi = 0; mi < 2; ++mi) {
          f32x4 cc = {};
          cc = __builtin_amdgcn_mfma_f32_16x16x32_bf16(aq[hh][mi][0], b0, cc, 0, 0, 0);
          cc = __builtin_amdgcn_mfma_f32_16x16x32_bf16(aq[hh][mi][1], b1, cc, 0, 0, 0);
          c[hh][mi] = cc;
        }
      }
#pragma unroll
      for (int mi = 0; mi < 2; ++mi)
#pragma unroll
        for (int r = 0; r < 4; ++r) {
          unsigned int pk = (unsigned int)f2bf(c[0][mi][r]) | ((unsigned int)f2bf(c[1][mi][r]) << 16);
          *(unsigned int*)&Ssh[(mi * 16 + lq * 4 + r) * SS_I + jt * SLOT + lm * SS_J + h0] = pk;
        }
    }
    __syncthreads();  // B1: scores ready; linv ready (iter 0); prev AV P-reads done
    // ---- premix -> E in place -> postmix (SWAPPED) -> Psh[g][i][j] ----
#pragma unroll
    for (int ii = 0; ii < 8; ++ii) {
      const int i_loc = wave * 4 + (ii & 3), jt = ii >> 2;
      unsigned short* srow = &Ssh[i_loc * SS_I + jt * SLOT];
      s16x8 bs;
#pragma unroll
      for (int t = 0; t < 8; ++t) bs[t] = 0;
      if (lq < 2) {
        s16x4 p0 = *(const s16x4*)(srow + lm * SS_J + lq * 8);
        s16x4 p1 = *(const s16x4*)(srow + lm * SS_J + lq * 8 + 4);
        bs[0] = p0[0]; bs[1] = p0[1]; bs[2] = p0[2]; bs[3] = p0[3];
        bs[4] = p1[0]; bs[5] = p1[1]; bs[6] = p1[2]; bs[7] = p1[3];
      }
      f32x4 c = {};
      c = __builtin_amdgcn_mfma_f32_16x16x32_bf16(apre, bs, c, 0, 0, 0);
      const float4 li = *(const float4*)&linv[i_loc * 16 + lq * 4];
      const float lif[4] = {li.x, li.y, li.z, li.w};
      s16x4 ep;
#pragma unroll
      for (int r = 0; r < 4; ++r)
        ep[r] = (short)f2bf(__expf(c[r] + bpre_r[r]) * lif[r]);
      *(s16x4*)(srow + lm * SS_J + lq * 4) = ep;  // E in place, [j][g] layout
      // postmix: A = E (m=j, k=g) read from [j][g]; B = wpost (n=g', k=g)
      s16x8 be;
#pragma unroll
      for (int t = 0; t < 8; ++t) be[t] = 0;
      if (lq < 2) {
        s16x4 q0 = *(const s16x4*)(srow + lm * SS_J + lq * 8);
        s16x4 q1 = *(const s16x4*)(srow + lm * SS_J + lq * 8 + 4);
        be[0] = q0[0]; be[1] = q0[1]; be[2] = q0[2]; be[3] = q0[3];
        be[4] = q1[0]; be[5] = q1[1]; be[6] = q1[2]; be[7] = q1[3];
      }
      f32x4 c2 = {};
      c2 = __builtin_amdgcn_mfma_f32_16x16x32_bf16(be, apost, c2, 0, 0, 0);
      // c2: row = lq*4+r = j (within jt tile), col = lm = g'
      s16x4 pv;
#pragma unroll
      for (int r = 0; r < 4; ++r) pv[r] = (short)f2bf(c2[r] + bpost_lm);
      *(s16x4*)&Psh[lm * PS_G + i_loc * PS_J + jt * 16 + lq * 4] = pv;  // b64
    }
    __syncthreads();  // B2: P complete
    // ---- AV: A = P[g][i][j] (b64 pair, full K=32), B = Vt global ----
#pragma unroll
    for (int g = 0; g < 2; ++g) {
      const int gg = h0 + g;
      s16x8 bv[4];
#pragma unroll
      for (int nd = 0; nd < 4; ++nd)
        bv[nd] = *(const s16x8*)&Vt[(((size_t)(b * H_ + gg) * D_) + nd * 16 + lm) * N_ + j0 + lq * 8];
#pragma unroll
      for (int mi = 0; mi < 2; ++mi) {
        const unsigned short* pb = &Psh[gg * PS_G + (mi * 16 + lm) * PS_J + lq * 8];
        s16x4 a0 = *(const s16x4*)pb;
        s16x4 a1 = *(const s16x4*)(pb + 4);
        s16x8 ap;
        ap[0] = a0[0]; ap[1] = a0[1]; ap[2] = a0[2]; ap[3] = a0[3];
        ap[4] = a1[0]; ap[5] = a1[1]; ap[6] = a1[2]; ap[7] = a1[3];
#pragma unroll
        for (int nd = 0; nd < 4; ++nd)
          acc[g][mi][nd] = __builtin_amdgcn_mfma_f32_16x16x32_bf16(ap, bv[nd], acc[g][mi][nd], 0, 0, 0);
      }
    }
  }
#pragma unroll
  for (int g = 0; g < 2; ++g)
#pragma unroll
    for (int mi = 0; mi < 2; ++mi)
#pragma unroll
      for (int nd = 0; nd < 4; ++nd)
#pragma unroll
        for (int r = 0; r < 4; ++r)
          Oout[((size_t)b * N_ + i0 + mi * 16 + lq * 4 + r) * 1024 + (h0 + g) * 64 + nd * 16 + lm] = acc[g][mi][nd][r];
}

extern "C" void kernel_launch(void* const* d_in, const int* in_sizes, int n_in,
                              void* d_out, int out_size, void* d_ws,
                              size_t ws_size, hipStream_t stream) {
  (void)in_sizes; (void)n_in; (void)out_size; (void)ws_size;
  const float* x      = (const float*)d_in[0];
  const float* w_qkv  = (const float*)d_in[1];
  const float* w_out  = (const float*)d_in[2];
  const float* w_pre  = (const float*)d_in[3];
  const float* b_pre  = (const float*)d_in[4];
  const float* w_post = (const float*)d_in[5];
  const float* b_post = (const float*)d_in[6];

  float* out = (float*)d_out;                        // (B,N,F) fp32
  float* kv  = out + (size_t)B_ * N_ * F_;           // (2,B,H,N,D) fp32

  unsigned short* xb  = (unsigned short*)d_ws;            // 4096x1024
  unsigned short* wqb = xb + (size_t)4096 * 1024;         // 3072x1024 (permuted)
  unsigned short* wob = wqb + (size_t)3072 * 1024;        // 1024x1024
  unsigned short* Qb  = wob + (size_t)1024 * 1024;        // (B,H,N,D)
  unsigned short* Kb  = Qb + (size_t)B_ * H_ * N_ * D_;
  unsigned short* Vt  = Kb + (size_t)B_ * H_ * N_ * D_;   // (B,H,D,N)
  unsigned short* O1  = Vt + (size_t)B_ * H_ * N_ * D_;   // (B,N,1024) bf16
  float* l_glob = (float*)(O1 + (size_t)B_ * N_ * F_);    // (B,N,16) fp32
  float* Oh = l_glob + (size_t)B_ * N_ * H_;              // 4 x (B,N,1024) fp32

  cvt_bf16<<<dim3(4096 * 1024 / 8 / 256), 256, 0, stream>>>(x, xb, 4096 * 1024 / 8);
  cvt_wqkv_perm<<<dim3(3072 * 128 / 256), 256, 0, stream>>>(w_qkv, wqb);
  cvt_bf16<<<dim3(1024 * 1024 / 8 / 256), 256, 0, stream>>>(w_out, wob, 1024 * 1024 / 8);
  hipMemsetAsync(l_glob, 0, (size_t)B_ * N_ * H_ * 4, stream);

  gemm_bf16<0><<<dim3(3072 / 128, 4096 / 128), 256, 0, stream>>>(xb, wqb, kv, Qb, Kb, Vt);

  attn_l<<<dim3(N_ / 32, 4, B_), 512, 0, stream>>>(Qb, Kb, w_pre, b_pre, l_glob);
  attn_av<<<dim3(N_ / 32, 4, B_), 512, 0, stream>>>(Qb, Kb, Vt, w_pre, b_pre, w_post, b_post,
                                                    l_glob, Oh);

  cvt_sum4<<<dim3(B_ * N_ * F_ / 4 / 256), 256, 0, stream>>>(Oh, O1);

  gemm_bf16<1><<<dim3(1024 / 128, 4096 / 128), 256, 0, stream>>>(O1, wob, out, nullptr, nullptr, nullptr);
}